// Round 7
// baseline (145.513 us; speedup 1.0000x reference)
//
#include <hip/hip_runtime.h>

#define HW_ (1024 * 1024)

typedef _Float16 half8 __attribute__((ext_vector_type(8)));
typedef float f32x4 __attribute__((ext_vector_type(4)));

// MFMA formulation: per 16-pixel row-segment, D[16px][16ch] = A[16px][32] x
// B[32taps][16ch] via one mfma_f32_16x16x32_f16 (taps 25..31 zero-padded).
//   A: lane provides row m=lane&15 (pixel), k=(lane>>4)*8+j   [m120]
//   B: lane provides col n=lane&15 (chan),  k=(lane>>4)*8+j   [dual of A]
//   D: lane holds chan c=lane&15, pixels (lane>>4)*4+reg      [m89/m91]
// Block = 256 thr (4 waves) owns a 32x32 output tile; wave w does rows
// w*8..w*8+7, one MFMA group per row (16 computed px, stride 2).
// Image tile staged once in LDS as fp16 (36 rows x 40 cols, halo 2).
// Dead taps gather from a zeroed LDS pad (R6 BUG: pad was zeroed with
// `if (tid<288)` under a 256-thread block -> smem[2208..2240) uninitialized
// -> exp2(garbage)=inf -> NaN. Fixed with a strided loop over all 288.)
// Softmax: no max-subtraction (|score| <~ 3: filters ~N(0,0.04^2), px<1);
// dual xor-reduce: low 8 lanes sum e*g while high 8 sum e in the same 3
// shuffles, then one xor-8 swap delivers Sum e to the low lanes.
__global__ __launch_bounds__(256, 2)
void demosaick_mfma(const float* __restrict__ mosaick,
                    const float* __restrict__ sel_filts,
                    const float* __restrict__ green_filts,
                    float* __restrict__ out) {
    // [0,1440): image tile 36 rows x 40 cols (fp16)
    // [1440,1952): fBT[16 ch][32 taps] (fp16), sel ch0-7, green ch8-15
    // [1952,2240): zero pad for dead-tap reads (a_idx 1952 + imm <= 2233)
    __shared__ __align__(16) _Float16 smem[2240];

    const int tid = threadIdx.x;
    const int b   = blockIdx.z;
    const int by0 = blockIdx.y * 32, bx0 = blockIdx.x * 32;
    const float* img = mosaick + (size_t)b * HW_;

    // ---- staging ----
    for (int idx = tid; idx < 1440; idx += 256) {
        int row = idx / 40, col = idx - row * 40;
        int gy = by0 - 2 + row; gy = gy < 0 ? 0 : (gy > 1023 ? 1023 : gy);
        int gx = bx0 - 2 + col; gx = gx < 0 ? 0 : (gx > 1023 ? 1023 : gx);
        smem[idx] = (_Float16)img[gy * 1024 + gx];
    }
    for (int idx = tid; idx < 512; idx += 256) {
        int ch = idx >> 5, t = idx & 31;
        float v = 0.f;
        if (t < 25) v = (ch < 8) ? sel_filts[ch * 25 + t]
                                 : green_filts[(ch - 8) * 25 + t];
        smem[1440 + idx] = (_Float16)v;
    }
    for (int idx = tid; idx < 288; idx += 256)   // R6 fix: cover ALL 288
        smem[1952 + idx] = (_Float16)0.f;
    __syncthreads();

    const int lane = tid & 63, w = tid >> 6;
    const int c = lane & 15, q = lane >> 4;   // c: chan (B/D) & pixel row (A)

    // B fragment: fBT[c][q*8..q*8+7], 16B contiguous -> ds_read_b128
    const half8 b8 = *(const half8*)&smem[1440 + c * 32 + q * 8];

    // Per-lane A gather addresses (half-element indices), loop-invariant.
    int a_idx[8];
    #pragma unroll
    for (int j = 0; j < 8; ++j) {
        int t = q * 8 + j;
        int dy = t / 5, dx = t - dy * 5;
        a_idx[j] = (t >= 25) ? 1952 : (w * 320 + dy * 40 + 2 * c + dx);
    }

    float* outp = out + (size_t)b * HW_;
    const float L2E = 1.44269504f;

    #pragma unroll
    for (int g = 0; g < 8; ++g) {
        // row r = w*8+g; y = by0+r; y parity = g parity (by0, w*8 even).
        // computed x parity: y even -> odd x (po=1); y odd -> even x (po=0).
        const int imm = g * 40 + ((g & 1) ? 0 : 1);

        half8 a8;
        #pragma unroll
        for (int j = 0; j < 8; ++j) a8[j] = smem[a_idx[j] + imm];

        f32x4 z = {0.f, 0.f, 0.f, 0.f};
        f32x4 acc = __builtin_amdgcn_mfma_f32_16x16x32_f16(a8, b8, z, 0, 0, 0);

        float gh[4];
        #pragma unroll
        for (int r = 0; r < 4; ++r) {
            float own = acc[r];
            float oth = __shfl_xor(own, 8);           // partner channel c^8
            float t0  = (c < 8) ? own : oth;          // sel score s_{c&7}
            float e   = __builtin_amdgcn_exp2f(t0 * L2E);
            float v   = (c < 8) ? e * oth : e;        // low: e*g, high: e
            v += __shfl_xor(v, 1);
            v += __shfl_xor(v, 2);
            v += __shfl_xor(v, 4);                    // low: Sum e*g, high: Sum e
            float sums = __shfl_xor(v, 8);            // low lanes receive Sum e
            gh[r] = v * __builtin_amdgcn_rcpf(sums);  // valid on c<8
        }

        if (c < 4) {
            int p = q * 4 + c;                        // pixel index 0..15
            float gv = (c == 0) ? gh[0] : (c == 1) ? gh[1]
                     : (c == 2) ? gh[2] : gh[3];
            // pass-through site: x%2==y%2; local tile col 2p+2+(g&1)
            float pass = (float)smem[(w * 8 + g + 2) * 40 + 2 * p + 2 + (g & 1)];
            float2 o;
            if (g & 1) { o.x = gv;   o.y = pass; }    // y odd: (green, pass)
            else       { o.x = pass; o.y = gv;   }    // y even: (pass, green)
            int y = by0 + w * 8 + g;
            *(float2*)(outp + (size_t)y * 1024 + bx0 + 2 * p) = o;
        }
    }
}

extern "C" void kernel_launch(void* const* d_in, const int* in_sizes, int n_in,
                              void* d_out, int out_size, void* d_ws, size_t ws_size,
                              hipStream_t stream) {
    const float* mosaick     = (const float*)d_in[0];
    const float* sel_filts   = (const float*)d_in[1];
    const float* green_filts = (const float*)d_in[2];
    float* out = (float*)d_out;
    const int B = in_sizes[0] / HW_;         // 8
    dim3 grid(1024 / 32, 1024 / 32, B);      // (32, 32, 8) = 8192 blocks
    dim3 block(256, 1, 1);
    hipLaunchKernelGGL(demosaick_mfma, grid, block, 0, stream,
                       mosaick, sel_filts, green_filts, out);
}

// Round 8
// 111.129 us; speedup vs baseline: 1.3094x; 1.3094x over previous
//
#include <hip/hip_runtime.h>

#define HW_ (1024 * 1024)

typedef _Float16 half8 __attribute__((ext_vector_type(8)));
typedef float f32x4 __attribute__((ext_vector_type(4)));

// FLIPPED MFMA (vs R7): D[16ch][16px] = A[16ch][32taps] x B[32taps][16px].
//   A (filters): lane m=lane&15 (channel), k=(lane>>4)*8+j -> one b128,
//     loop-invariant (fBT[ch][32] layout, 16B aligned).
//   B (image):   lane n=lane&15 (pixel),  k=(lane>>4)*8+j -> 8 ds_read_u16
//     (identical addresses to R7's A gather; d16/d16_hi packing).
//   D: col=lane&15 = pixel, row=(lane>>4)*4+reg = channel  [m89/m91].
// So lane (c,q) holds 4 consecutive CHANNELS of pixel c in registers:
//   q=0: sel ch0-3, q=1: sel ch4-7, q=2: green ch0-3, q=3: green ch4-7.
// Softmax epilogue is now mostly in-register: 4 xor-32 shuffles route green
// partners to sel lanes, 4 exp2+fma accumulate e & e*g, 2 xor-16 shuffles
// combine the channel halves -> 6 shuffles/group vs R7's 20 (R7 was
// DS-pipe-bound: 2.88M bank conflicts, 224 DS instrs/wave ~ 69 us).
// Dead taps (k>=25): filter side is ZERO (staged so), image side reads a
// zero pad -> product 0 regardless.
__global__ __launch_bounds__(256, 2)
void demosaick_mfma(const float* __restrict__ mosaick,
                    const float* __restrict__ sel_filts,
                    const float* __restrict__ green_filts,
                    float* __restrict__ out) {
    // [0,1440): image tile 36 rows x 40 cols (fp16)
    // [1440,1952): fBT[16 ch][32 taps] (fp16), sel ch0-7, green ch8-15
    // [1952,2240): zero pad for dead-tap image reads (1952 + imm <= 2233)
    __shared__ __align__(16) _Float16 smem[2240];

    const int tid = threadIdx.x;
    const int b   = blockIdx.z;
    const int by0 = blockIdx.y * 32, bx0 = blockIdx.x * 32;
    const float* img = mosaick + (size_t)b * HW_;

    // ---- staging ----
    for (int idx = tid; idx < 1440; idx += 256) {
        int row = idx / 40, col = idx - row * 40;
        int gy = by0 - 2 + row; gy = gy < 0 ? 0 : (gy > 1023 ? 1023 : gy);
        int gx = bx0 - 2 + col; gx = gx < 0 ? 0 : (gx > 1023 ? 1023 : gx);
        smem[idx] = (_Float16)img[gy * 1024 + gx];
    }
    for (int idx = tid; idx < 512; idx += 256) {
        int ch = idx >> 5, t = idx & 31;
        float v = 0.f;
        if (t < 25) v = (ch < 8) ? sel_filts[ch * 25 + t]
                                 : green_filts[(ch - 8) * 25 + t];
        smem[1440 + idx] = (_Float16)v;
    }
    for (int idx = tid; idx < 288; idx += 256)
        smem[1952 + idx] = (_Float16)0.f;
    __syncthreads();

    const int lane = tid & 63, w = tid >> 6;
    const int c = lane & 15, q = lane >> 4;   // c: channel(A) & pixel(B/D)

    // A fragment (filters): fBT[c][q*8..q*8+7] -> ds_read_b128, loop-invariant
    const half8 afrag = *(const half8*)&smem[1440 + c * 32 + q * 8];

    // B gather addresses (image, pixel n=c, taps q*8+j), loop-invariant.
    int b_idx[8];
    #pragma unroll
    for (int j = 0; j < 8; ++j) {
        int t = q * 8 + j;
        int dy = t / 5, dx = t - dy * 5;
        b_idx[j] = (t >= 25) ? 1952 : (w * 320 + dy * 40 + 2 * c + dx);
    }

    float* outp = out + (size_t)b * HW_;
    const float L2E = 1.44269504f;

    #pragma unroll
    for (int g = 0; g < 8; ++g) {
        // row y = by0 + w*8 + g; y parity = g parity.
        // computed x parity: y even -> odd x (po=1); y odd -> even x (po=0).
        const int imm = g * 40 + ((g & 1) ? 0 : 1);

        half8 b8;
        #pragma unroll
        for (int j = 0; j < 8; ++j) b8[j] = smem[b_idx[j] + imm];

        f32x4 z = {0.f, 0.f, 0.f, 0.f};
        f32x4 acc = __builtin_amdgcn_mfma_f32_16x16x32_f16(afrag, b8, z, 0, 0, 0);

        // acc[r] = D[ch = q*4+r][px = c]
        float eg = 0.f, se = 0.f;
        #pragma unroll
        for (int r = 0; r < 4; ++r) {
            float goth = __shfl_xor(acc[r], 32);      // green partner (valid on q<2)
            float e = __builtin_amdgcn_exp2f(acc[r] * L2E);
            eg = fmaf(e, goth, eg);
            se += e;
        }
        eg += __shfl_xor(eg, 16);                     // combine q0<->q1 halves
        se += __shfl_xor(se, 16);
        float gh = eg * __builtin_amdgcn_rcpf(se);    // valid on q==0 (and q==1)

        if (q == 0) {
            // pixel p = c; pass-through at tile col 2c+2+(g&1)
            float pass = (float)smem[(w * 8 + g + 2) * 40 + 2 * c + 2 + (g & 1)];
            float2 o;
            if (g & 1) { o.x = gh;   o.y = pass; }    // y odd: (green, pass)
            else       { o.x = pass; o.y = gh;   }    // y even: (pass, green)
            int y = by0 + w * 8 + g;
            *(float2*)(outp + (size_t)y * 1024 + bx0 + 2 * c) = o;
        }
    }
}

extern "C" void kernel_launch(void* const* d_in, const int* in_sizes, int n_in,
                              void* d_out, int out_size, void* d_ws, size_t ws_size,
                              hipStream_t stream) {
    const float* mosaick     = (const float*)d_in[0];
    const float* sel_filts   = (const float*)d_in[1];
    const float* green_filts = (const float*)d_in[2];
    float* out = (float*)d_out;
    const int B = in_sizes[0] / HW_;         // 8
    dim3 grid(1024 / 32, 1024 / 32, B);      // (32, 32, 8) = 8192 blocks
    dim3 block(256, 1, 1);
    hipLaunchKernelGGL(demosaick_mfma, grid, block, 0, stream,
                       mosaick, sel_filts, green_filts, out);
}